// Round 2
// baseline (378.182 us; speedup 1.0000x reference)
//
#include <hip/hip_runtime.h>
#include <math.h>

#define N_   64
#define C_   512
#define HW_  1024
#define K_   64
#define ALPHA_ 50.0f
#define EPS_  1e-12f

// d_out float offsets
#define OUT_VLAD 0
#define OUT_SA   2097152     // N*K*C
#define OUT_FEAT 6291456     // + N*K*HW

// ws byte offsets (~152.7 MB; ws poison fills show ~637 MB allocated)
#define WSB_WT    0           // fp32 [K][C]           131072 B
#define WSB_WNTB  131072      // bf16 [K][C]            65536 B
#define WSB_A     196608      // bf16 [N][K][HW]      8388608 B
#define WSB_SAP   8585216     // fp32 [N][16][K]       262144 B  (sumA partials)
#define WSB_PART  8847360     // fp32 2x[N][K][C]    16777216 B
#define WSB_FEATB 25624576    // bf16 [N][HW][C]     67108864 B
#define WSB_XNB   92733440    // bf16 [N][C][HW]     67108864 B
#define PART_ELEMS 2097152    // floats per partial copy

typedef __attribute__((ext_vector_type(8))) __bf16 bf16x8;
typedef __attribute__((ext_vector_type(4))) float f32x4;

__device__ inline unsigned short f2bf(float f) {
    unsigned int u = __builtin_bit_cast(unsigned int, f);
    u = (u + 0x7FFFu + ((u >> 16) & 1u)) >> 16;
    return (unsigned short)u;
}
__device__ inline f32x4 mfma16(const unsigned short* pa, const unsigned short* pb, f32x4 c) {
    bf16x8 a = *(const bf16x8*)pa;
    bf16x8 b = *(const bf16x8*)pb;
    return __builtin_amdgcn_mfma_f32_16x16x32_bf16(a, b, c, 0, 0, 0);
}

// ---------------- K1: weight column norms -> wT fp32, wnTb bf16, both [K][C]
__global__ __launch_bounds__(256) void k1_weights(const float* __restrict__ W,
                                                  float* __restrict__ wT,
                                                  unsigned short* __restrict__ wnTb) {
    int k = blockIdx.x;
    int t = threadIdx.x;
    __shared__ float red[256];
    float s = 0.f;
    for (int c = t; c < C_; c += 256) { float w = W[c * K_ + k]; s += w * w; }
    red[t] = s;
    __syncthreads();
    for (int st = 128; st > 0; st >>= 1) {
        if (t < st) red[t] += red[t + st];
        __syncthreads();
    }
    float inv = 1.f / fmaxf(sqrtf(red[0]), EPS_);
    for (int c = t; c < C_; c += 256) {
        float w = W[c * K_ + k];
        wT[k * C_ + c]   = w;
        wnTb[k * C_ + c] = f2bf(w * inv);
    }
}

// ---------------- K2: L2-normalize x over C. Emits:
//   feat  fp32 [N][HW][C]  (required output)
//   featb bf16 [N][HW][C]  (K3 A-operand, pre-converted)
//   xnb   bf16 [N][C][HW]  (K4 B-operand, pre-scaled + pre-converted)
__global__ __launch_bounds__(256) void k2_normfeat(const float* __restrict__ x,
                                                   float* __restrict__ out,
                                                   unsigned short* __restrict__ featb,
                                                   unsigned short* __restrict__ xnb) {
    float* feat = out + OUT_FEAT;
    int b   = blockIdx.x;
    int n   = b >> 6;
    int hw0 = (b & 63) << 4;
    int t   = threadIdx.x;
    __shared__ float Xs[C_ * 17 + 256 + 16];
    float* red = Xs + C_ * 17;
    float* nrm = red + 256;
    const float* xn = x + (long)n * C_ * HW_;
    for (int j = 0; j < 32; ++j) {
        int idx = j * 256 + t;
        int c = idx >> 4, p = idx & 15;
        Xs[c * 17 + p] = xn[c * HW_ + hw0 + p];
    }
    __syncthreads();
    {
        int p = t & 15, cg = t >> 4;
        float s = 0.f;
        for (int j = 0; j < 32; ++j) {
            float v = Xs[(cg + 16 * j) * 17 + p];
            s += v * v;
        }
        red[t] = s;
    }
    __syncthreads();
    if (t < 16) {
        float s = 0.f;
        for (int g = 0; g < 16; ++g) s += red[g * 16 + t];
        nrm[t] = 1.f / fmaxf(sqrtf(s), EPS_);
    }
    __syncthreads();
    // fp32 feature output (transposed, coalesced)
    float* frow = feat + ((long)n * HW_ + hw0) * C_;
    for (int p = 0; p < 16; ++p) {
        float iv = nrm[p];
        frow[(long)p * C_ + t]       = Xs[t * 17 + p] * iv;
        frow[(long)p * C_ + t + 256] = Xs[(t + 256) * 17 + p] * iv;
    }
    // bf16 feature copy [h][c], c-pairs packed as u32 (coalesced)
    unsigned int* fbp = (unsigned int*)featb;
    for (int j = 0; j < 16; ++j) {
        int idx = j * 256 + t;
        int p = idx >> 8, cp = idx & 255;
        float iv = nrm[p];
        unsigned int lo = f2bf(Xs[(2 * cp) * 17 + p] * iv);
        unsigned int hi = f2bf(Xs[(2 * cp + 1) * 17 + p] * iv);
        fbp[((long)n * HW_ + hw0 + p) * 256 + cp] = lo | (hi << 16);
    }
    // bf16 normalized-x copy [c][h], h-pairs packed as u32 (32B rows)
    unsigned int* xbp = (unsigned int*)xnb;
    for (int j = 0; j < 16; ++j) {
        int idx = j * 256 + t;
        int c = idx >> 3, hp = idx & 7;
        unsigned int lo = f2bf(Xs[c * 17 + 2 * hp]     * nrm[2 * hp]);
        unsigned int hi = f2bf(Xs[c * 17 + 2 * hp + 1] * nrm[2 * hp + 1]);
        xbp[((long)n * C_ + c) * 512 + (hw0 >> 1) + hp] = lo | (hi << 16);
    }
}

// ---------------- K3: MFMA GEMM1 (logits = featb . WnT) + softmax -> sa, A(bf16)
// 64-pixel tiles, grid = 64n x 16 tiles = 1024 blocks. Staging = pure bf16 copy.
#define K3PITCH 136   // bf16 elems; 272 B row, 16B aligned
__global__ __launch_bounds__(256, 4) void k3_sa(const unsigned short* __restrict__ featb,
                                                const unsigned short* __restrict__ wnTb,
                                                const float* __restrict__ bias,
                                                float* __restrict__ sa,
                                                unsigned short* __restrict__ Ab,
                                                float* __restrict__ sumA_part) {
    __shared__ alignas(16) unsigned short sm[64 * K3PITCH + 64 * K3PITCH]; // 34816 B
    unsigned short* Fsh = sm;                  // [64 p][128 c] per chunk
    unsigned short* Wsh = sm + 64 * K3PITCH;   // [64 k][128 c] per chunk
    // phase-2 overlay (19456 B < 34816 B)
    float* Ls = (float*)sm;        // [64 kc][66 p-pitch]
    float* Bz = Ls + 64 * 66;      // [64]
    float* Zm = Bz + 64;           // [64]
    float* Iv = Zm + 64;           // [64]
    float* Rm = Iv + 64;           // [4][64]
    float* Rs = Rm + 256;          // [4][64]

    int b    = blockIdx.x;
    int n    = b >> 4;
    int tile = b & 15;
    int hw0  = tile << 6;
    int t    = threadIdx.x;
    int l    = t & 63, w = t >> 6;
    int mr   = l & 15, q = l >> 4;

    f32x4 acc[4];
#pragma unroll
    for (int j = 0; j < 4; ++j) acc[j] = (f32x4){0.f, 0.f, 0.f, 0.f};

    const unsigned short* fb = featb + ((long)n * HW_ + hw0) * C_;
    for (int ch = 0; ch < 4; ++ch) {
        int c0 = ch * 128;
        __syncthreads();
#pragma unroll
        for (int j = 0; j < 4; ++j) {          // Fsh: 64p x 128c bf16 copy
            int idx = j * 256 + t;
            int row = idx >> 4, sg = idx & 15;
            *(uint4*)(Fsh + row * K3PITCH + sg * 8) =
                *(const uint4*)(fb + (long)row * C_ + c0 + sg * 8);
        }
#pragma unroll
        for (int j = 0; j < 4; ++j) {          // Wsh: 64k x 128c bf16 copy
            int idx = j * 256 + t;
            int row = idx >> 4, sg = idx & 15;
            *(uint4*)(Wsh + row * K3PITCH + sg * 8) =
                *(const uint4*)(wnTb + row * C_ + c0 + sg * 8);
        }
        __syncthreads();
#pragma unroll
        for (int ks = 0; ks < 4; ++ks) {
            int ko = ks * 32 + q * 8;
            const unsigned short* ap = Fsh + (w * 16 + mr) * K3PITCH + ko;
#pragma unroll
            for (int j = 0; j < 4; ++j) {
                const unsigned short* bp = Wsh + (j * 16 + mr) * K3PITCH + ko;
                acc[j] = mfma16(ap, bp, acc[j]);
            }
        }
    }
    __syncthreads();
    // dump logits: acc[j][r] = logit(p = w*16 + q*4 + r, k = j*16 + mr)
#pragma unroll
    for (int j = 0; j < 4; ++j)
#pragma unroll
        for (int r = 0; r < 4; ++r)
            Ls[(j * 16 + mr) * 66 + w * 16 + q * 4 + r] = acc[j][r];
    if (t < 64) Bz[t] = bias[t];
    __syncthreads();
    // softmax over kc (64) per pixel p (64), all 256 threads active
    {
        int p = t & 63, g = t >> 6;
        float mx = -1e30f;
#pragma unroll
        for (int kk = 0; kk < 16; ++kk) {
            int kc = g * 16 + kk;
            float z = (Ls[kc * 66 + p] + Bz[kc]) * ALPHA_;
            mx = fmaxf(mx, z);
        }
        Rm[g * 64 + p] = mx;
        __syncthreads();
        float M = fmaxf(fmaxf(Rm[p], Rm[64 + p]), fmaxf(Rm[128 + p], Rm[192 + p]));
        float s = 0.f;
#pragma unroll
        for (int kk = 0; kk < 16; ++kk) {
            int kc = g * 16 + kk;
            float z = (Ls[kc * 66 + p] + Bz[kc]) * ALPHA_;
            s += __expf(z - M);
        }
        Rs[g * 64 + p] = s;
        __syncthreads();
        if (g == 0) {
            Zm[p] = M;
            Iv[p] = 1.f / (Rs[p] + Rs[64 + p] + Rs[128 + p] + Rs[192 + p]);
        }
    }
    __syncthreads();
    float* sab = sa + (long)n * K_ * HW_ + hw0;
    unsigned short* Arow = Ab + (long)n * K_ * HW_ + hw0;
#pragma unroll
    for (int j = 0; j < 8; ++j) {              // p-pairs: float2 sa, u32 Ab
        int idx = j * 256 + t;
        int kc = idx >> 5, pp = idx & 31;
        int p = pp * 2;
        float2 v = *(const float2*)(Ls + kc * 66 + p);
        *(float2*)(sab + (long)kc * HW_ + p) = v;
        float a0 = __expf((v.x + Bz[kc]) * ALPHA_ - Zm[p])     * Iv[p];
        float a1 = __expf((v.y + Bz[kc]) * ALPHA_ - Zm[p + 1]) * Iv[p + 1];
        *(unsigned int*)(Arow + (long)kc * HW_ + p) =
            (unsigned int)f2bf(a0) | ((unsigned int)f2bf(a1) << 16);
        Ls[kc * 66 + p]     = a0;              // overwrite logits with a
        Ls[kc * 66 + p + 1] = a1;
    }
    __syncthreads();
    if (t < 64) {                              // per-block partial sumA over 64 pixels
        float s = 0.f;
        for (int p2 = 0; p2 < 64; ++p2) s += Ls[t * 66 + p2];
        sumA_part[((long)n * 16 + tile) * 64 + t] = s;
    }
}

// ---------------- K4: MFMA GEMM2 vlad_raw = A . xnb  (both bf16, pure-copy staging)
// 64-c tiles, grid = 64n x (8 c-tiles x 2 h-halves) = 1024 blocks.
#define K4PITCH 72    // bf16; 144 B rows, 16B aligned
__global__ __launch_bounds__(256, 4) void k4_vlad(const unsigned short* __restrict__ xnb,
                                                  const unsigned short* __restrict__ Ab,
                                                  float* __restrict__ part) {
    __shared__ alignas(16) unsigned short Ash[64 * K4PITCH];    // 9216 B
    __shared__ alignas(16) unsigned short Fsh[64 * K4PITCH];    // 9216 B
    int b  = blockIdx.x;
    int n  = b >> 4;
    int r  = b & 15;
    int c_off  = (r & 7) * 64;
    int hh     = r >> 3;
    int h_base = hh * 512;
    int t = threadIdx.x;
    int l = t & 63, w = t >> 6;
    int mr = l & 15, q = l >> 4;
    int kcb = (w >> 1) * 32, cb = (w & 1) * 32;

    f32x4 acc[2][2];
#pragma unroll
    for (int i = 0; i < 2; ++i)
#pragma unroll
        for (int j = 0; j < 2; ++j) acc[i][j] = (f32x4){0.f, 0.f, 0.f, 0.f};

    const unsigned short* Abase = Ab + (long)n * K_ * HW_ + h_base;
    const unsigned short* xb    = xnb + ((long)n * C_ + c_off) * HW_ + h_base;

    for (int ch = 0; ch < 8; ++ch) {
        int h0 = ch * 64;
        __syncthreads();
#pragma unroll
        for (int j = 0; j < 2; ++j) {          // Ash: 64kc x 64h bf16 copy
            int idx = j * 256 + t;
            int row = idx >> 3, sg = idx & 7;
            *(uint4*)(Ash + row * K4PITCH + sg * 8) =
                *(const uint4*)(Abase + (long)row * HW_ + h0 + sg * 8);
        }
#pragma unroll
        for (int j = 0; j < 2; ++j) {          // Fsh: 64c x 64h bf16 copy
            int idx = j * 256 + t;
            int row = idx >> 3, sg = idx & 7;
            *(uint4*)(Fsh + row * K4PITCH + sg * 8) =
                *(const uint4*)(xb + (long)row * HW_ + h0 + sg * 8);
        }
        __syncthreads();
#pragma unroll
        for (int ks = 0; ks < 2; ++ks) {
            int ko = ks * 32 + q * 8;
            const unsigned short* ap0 = Ash + (kcb + mr) * K4PITCH + ko;
            const unsigned short* ap1 = Ash + (kcb + 16 + mr) * K4PITCH + ko;
#pragma unroll
            for (int j = 0; j < 2; ++j) {
                const unsigned short* bp = Fsh + (cb + j * 16 + mr) * K4PITCH + ko;
                acc[0][j] = mfma16(ap0, bp, acc[0][j]);
                acc[1][j] = mfma16(ap1, bp, acc[1][j]);
            }
        }
    }
    float* pb = part + (long)hh * PART_ELEMS + (long)n * K_ * C_ + c_off;
#pragma unroll
    for (int i = 0; i < 2; ++i)
#pragma unroll
        for (int j = 0; j < 2; ++j)
#pragma unroll
            for (int rr = 0; rr < 4; ++rr) {
                int kc = kcb + i * 16 + q * 4 + rr;
                int c  = cb + j * 16 + mr;
                pb[(long)kc * C_ + c] = acc[i][j][rr];
            }
}

// ---------------- K5: combine 2 partials, subtract sumA*W, intra-normalize
__global__ __launch_bounds__(256) void k5_norm(const float* __restrict__ part,
                                               const float* __restrict__ sumA_part,
                                               const float* __restrict__ wT,
                                               float* __restrict__ vlad) {
    __shared__ float red[256];
    __shared__ float sred[16];
    int row = blockIdx.x;        // n*64 + kc
    int kc  = row & 63;
    int n   = row >> 6;
    int t   = threadIdx.x;
    if (t < 16) sred[t] = sumA_part[((long)n * 16 + t) * 64 + kc];
    __syncthreads();
    float sA = 0.f;
#pragma unroll
    for (int i = 0; i < 16; ++i) sA += sred[i];
    long base = (long)row * C_;
    float v0, v1;
    {
        int c = t;
        float s = part[base + c] + part[PART_ELEMS + base + c];
        v0 = s - sA * wT[kc * C_ + c];
    }
    {
        int c = t + 256;
        float s = part[base + c] + part[PART_ELEMS + base + c];
        v1 = s - sA * wT[kc * C_ + c];
    }
    red[t] = v0 * v0 + v1 * v1;
    __syncthreads();
    for (int st = 128; st > 0; st >>= 1) {
        if (t < st) red[t] += red[t + st];
        __syncthreads();
    }
    float inv = 1.f / fmaxf(sqrtf(red[0]), EPS_);
    vlad[base + t]       = v0 * inv;
    vlad[base + t + 256] = v1 * inv;
}

extern "C" void kernel_launch(void* const* d_in, const int* in_sizes, int n_in,
                              void* d_out, int out_size, void* d_ws, size_t ws_size,
                              hipStream_t stream) {
    const float* x    = (const float*)d_in[0];
    const float* W    = (const float*)d_in[1];
    const float* bias = (const float*)d_in[2];
    float* out = (float*)d_out;
    char* wsb  = (char*)d_ws;

    float* wT            = (float*)(wsb + WSB_WT);
    unsigned short* wnTb = (unsigned short*)(wsb + WSB_WNTB);
    unsigned short* Ab   = (unsigned short*)(wsb + WSB_A);
    float* sumA_part     = (float*)(wsb + WSB_SAP);
    float* part          = (float*)(wsb + WSB_PART);
    unsigned short* featb = (unsigned short*)(wsb + WSB_FEATB);
    unsigned short* xnb   = (unsigned short*)(wsb + WSB_XNB);

    float* vlad = out + OUT_VLAD;
    float* sa   = out + OUT_SA;

    hipLaunchKernelGGL(k1_weights,  dim3(64),   dim3(256), 0, stream, W, wT, wnTb);
    hipLaunchKernelGGL(k2_normfeat, dim3(4096), dim3(256), 0, stream, x, out, featb, xnb);
    hipLaunchKernelGGL(k3_sa,       dim3(1024), dim3(256), 0, stream, featb, wnTb, bias, sa, Ab, sumA_part);
    hipLaunchKernelGGL(k4_vlad,     dim3(1024), dim3(256), 0, stream, xnb, Ab, part);
    hipLaunchKernelGGL(k5_norm,     dim3(4096), dim3(256), 0, stream, part, sumA_part, wT, vlad);
}

// Round 4
// 339.003 us; speedup vs baseline: 1.1156x; 1.1156x over previous
//
#include <hip/hip_runtime.h>
#include <math.h>

#define N_   64
#define C_   512
#define HW_  1024
#define K_   64
#define ALPHA_ 50.0f
#define EPS_  1e-12f

// d_out float offsets
#define OUT_VLAD 0
#define OUT_SA   2097152     // N*K*C
#define OUT_FEAT 6291456     // + N*K*HW

// ws byte offsets (~26.7 MB)
#define WSB_WT    0           // fp32 [K][C]           131072 B
#define WSB_WNTB  131072      // bf16 [K][C]            65536 B
#define WSB_INVN  196608      // fp32 [N][HW]          262144 B
#define WSB_A     458752      // bf16 [N][K][HW]      8388608 B
#define WSB_SAP   8847360     // fp32 [N][64][64]      1048576 B (sumA partials)
#define WSB_PART  9895936     // fp32 2x[N][K][C]    16777216 B
#define PART_ELEMS 2097152    // floats per partial copy

typedef __attribute__((ext_vector_type(8))) __bf16 bf16x8;
typedef __attribute__((ext_vector_type(4))) float f32x4;
typedef __attribute__((ext_vector_type(8))) unsigned short ushort8v;

__device__ inline unsigned short f2bf(float f) {
    unsigned int u = __builtin_bit_cast(unsigned int, f);
    u = (u + 0x7FFFu + ((u >> 16) & 1u)) >> 16;
    return (unsigned short)u;
}
__device__ inline f32x4 mfma16(const unsigned short* pa, const unsigned short* pb, f32x4 c) {
    bf16x8 a = *(const bf16x8*)pa;
    bf16x8 b = *(const bf16x8*)pb;
    return __builtin_amdgcn_mfma_f32_16x16x32_bf16(a, b, c, 0, 0, 0);
}

// ---------------- K1: weight column norms -> wT fp32, wnTb bf16, both [K][C]
__global__ __launch_bounds__(256) void k1_weights(const float* __restrict__ W,
                                                  float* __restrict__ wT,
                                                  unsigned short* __restrict__ wnTb) {
    int k = blockIdx.x;
    int t = threadIdx.x;
    __shared__ float red[256];
    float s = 0.f;
    for (int c = t; c < C_; c += 256) { float w = W[c * K_ + k]; s += w * w; }
    red[t] = s;
    __syncthreads();
    for (int st = 128; st > 0; st >>= 1) {
        if (t < st) red[t] += red[t + st];
        __syncthreads();
    }
    float inv = 1.f / fmaxf(sqrtf(red[0]), EPS_);
    for (int c = t; c < C_; c += 256) {
        float w = W[c * K_ + k];
        wT[k * C_ + c]   = w;
        wnTb[k * C_ + c] = f2bf(w * inv);
    }
}

// ---------------- K23: fused normalize + feat write + GEMM1 + softmax
// Block = (n, 16-pixel tile). Grid 4096. float4 global loads, swizzled LDS.
// Outputs: feat (fp32), invn, sa (logits), Ab (bf16 softmax), sumA partials.
#define FPITCH 520   // bf16 elems per Fsh row (1040 B, 16B-aligned)
#define LSP    20    // Ls pitch (floats)
__global__ __launch_bounds__(256, 3) void k23_fused(const float* __restrict__ x,
                                                    const unsigned short* __restrict__ wnTb,
                                                    const float* __restrict__ bias,
                                                    float* __restrict__ out,
                                                    float* __restrict__ invn,
                                                    unsigned short* __restrict__ Ab,
                                                    float* __restrict__ sumA_part) {
    __shared__ alignas(16) char smraw[32768 + 128 + 16640];   // 49536 B -> 3 blocks/CU
    float* Xs            = (float*)smraw;                     // [512 c][16 p] fp32, quad-XOR-swizzled
    unsigned short* Wsh  = (unsigned short*)smraw;            // GEMM-phase alias [64 k][136]
    float* invsh         = (float*)(smraw + 32768);           // [16]
    unsigned short* FshB = (unsigned short*)(smraw + 32896);  // [16 p][520] bf16 (A-operand)
    f32x4* red4          = (f32x4*)(smraw + 32896);           // load-phase alias (4 KB)
    float* Ls            = (float*)(smraw + 32896);           // softmax alias [64 kc][20]
    float* Bz = Ls + 64 * LSP;    // [64]
    float* Zm = Bz + 64;          // [16]
    float* Iv = Zm + 16;          // [16]
    float* Rm = Iv + 16;          // [16][18]
    float* Rs = Rm + 288;         // [16][18]

    int b = blockIdx.x;
    int n = b >> 6, tile = b & 63;
    int hw0 = tile << 4;
    int t = threadIdx.x;
    int l = t & 63;
    int mr = l & 15, q = l >> 4;

    // ---- phase 1: float4 loads + square accumulate + swizzled LDS store
    const float* xb = x + (long)n * C_ * HW_ + hw0;
    int qv = t & 3, cbase = t >> 2;          // thread owns pixel-quad qv, c = cbase + 64j
    int qs = qv ^ (cbase & 3);               // XOR quad-slot swizzle
    f32x4 sq = (f32x4){0.f, 0.f, 0.f, 0.f};
    f32x4* Xs4 = (f32x4*)Xs;
#pragma unroll
    for (int j = 0; j < 8; ++j) {
        int c = cbase + 64 * j;
        f32x4 v = *(const f32x4*)(xb + (long)c * HW_ + qv * 4);
        sq += v * v;
        Xs4[c * 4 + qs] = v;
    }
    red4[t] = sq;
    __syncthreads();
    if (t < 128) red4[t] += red4[t + 128]; __syncthreads();
    if (t < 64)  red4[t] += red4[t + 64];  __syncthreads();
    if (t < 32)  red4[t] += red4[t + 32];  __syncthreads();
    if (t < 16)  red4[t] += red4[t + 16];  __syncthreads();
    if (t < 8)   red4[t] += red4[t + 8];   __syncthreads();
    if (t < 4)   red4[t] += red4[t + 4];   __syncthreads();
    if (t < 16) {
        float s  = ((float*)red4)[t];                 // pixel p = t
        float iv = 1.f / fmaxf(sqrtf(s), EPS_);
        invsh[t] = iv;
        invn[(long)n * HW_ + hw0 + t] = iv;
    }
    __syncthreads();

    // ---- phase 2: feat fp32 write (float4 along c) + Fsh bf16 A-operand build
    {
        float* frow = out + OUT_FEAT + ((long)n * HW_ + hw0) * C_;
        int p = t & 15, cg = t >> 4;
        float iv = invsh[p];
        int ql = p >> 2, pr = p & 3;
#pragma unroll
        for (int j = 0; j < 8; ++j) {
            int c0 = 64 * j + cg * 4;
            float f0 = Xs[(c0    ) * 16 + ((ql ^ 0) << 2) + pr] * iv;
            float f1 = Xs[(c0 + 1) * 16 + ((ql ^ 1) << 2) + pr] * iv;
            float f2 = Xs[(c0 + 2) * 16 + ((ql ^ 2) << 2) + pr] * iv;
            float f3 = Xs[(c0 + 3) * 16 + ((ql ^ 3) << 2) + pr] * iv;
            f32x4 fv = (f32x4){f0, f1, f2, f3};
            *(f32x4*)(frow + (long)p * C_ + c0) = fv;
            uint2 u;
            u.x = (unsigned)f2bf(f0) | ((unsigned)f2bf(f1) << 16);
            u.y = (unsigned)f2bf(f2) | ((unsigned)f2bf(f3) << 16);
            *(uint2*)(FshB + p * FPITCH + c0) = u;
        }
    }

    // ---- phase 3: GEMM1 (16px x 64k over 512c), W chunks staged into Xs region
    f32x4 acc[4];
#pragma unroll
    for (int j = 0; j < 4; ++j) acc[j] = (f32x4){0.f, 0.f, 0.f, 0.f};
    for (int ch = 0; ch < 4; ++ch) {
        int c0 = ch * 128;
        __syncthreads();                      // Xs/Wsh region safe to overwrite
#pragma unroll
        for (int j = 0; j < 4; ++j) {         // Wsh: 64k x 128c bf16 copy (L2-resident)
            int idx = j * 256 + t;
            int row = idx >> 4, sg = idx & 15;
            *(uint4*)(Wsh + row * 136 + sg * 8) =
                *(const uint4*)(wnTb + row * C_ + c0 + sg * 8);
        }
        __syncthreads();
#pragma unroll
        for (int ks = 0; ks < 4; ++ks) {
            const unsigned short* ap = FshB + mr * FPITCH + c0 + ks * 32 + q * 8;
#pragma unroll
            for (int j = 0; j < 4; ++j) {
                const unsigned short* bp = Wsh + (j * 16 + mr) * 136 + ks * 32 + q * 8;
                acc[j] = mfma16(ap, bp, acc[j]);
            }
        }
    }
    __syncthreads();                          // all MFMA done before Ls overlays FshB

    // ---- phase 4: softmax over 64 kc for 16 px
#pragma unroll
    for (int j = 0; j < 4; ++j)
#pragma unroll
        for (int r = 0; r < 4; ++r)
            Ls[(j * 16 + mr) * LSP + q * 4 + r] = acc[j][r];   // kc = j*16+mr, p = q*4+r
    if (t < 64) Bz[t] = bias[t];
    __syncthreads();
    {
        int p = t & 15, g = t >> 4;           // 16 groups x 4 kc each
        float mx = -1e30f;
#pragma unroll
        for (int kk = 0; kk < 4; ++kk) {
            int kc = g * 4 + kk;
            float z = (Ls[kc * LSP + p] + Bz[kc]) * ALPHA_;
            mx = fmaxf(mx, z);
        }
        Rm[g * 18 + p] = mx;
    }
    __syncthreads();
    if (t < 16) {
        float M = -1e30f;
#pragma unroll
        for (int g = 0; g < 16; ++g) M = fmaxf(M, Rm[g * 18 + t]);
        Zm[t] = M;
    }
    __syncthreads();
    {
        int p = t & 15, g = t >> 4;
        float M = Zm[p];
        float s = 0.f;
#pragma unroll
        for (int kk = 0; kk < 4; ++kk) {
            int kc = g * 4 + kk;
            float z = (Ls[kc * LSP + p] + Bz[kc]) * ALPHA_;
            s += __expf(z - M);
        }
        Rs[g * 18 + p] = s;
    }
    __syncthreads();
    if (t < 16) {
        float S = 0.f;
#pragma unroll
        for (int g = 0; g < 16; ++g) S += Rs[g * 18 + t];
        Iv[t] = 1.f / S;
    }
    __syncthreads();

    // ---- phase 5: outputs (sa float4, Ab packed bf16) + sumA partials
    float* sab = out + OUT_SA + (long)n * K_ * HW_ + hw0;
    unsigned short* Arow = Ab + (long)n * K_ * HW_ + hw0;
    {
        int kc = t >> 2, p0 = (t & 3) * 4;
        f32x4 v = *(f32x4*)(Ls + kc * LSP + p0);
        *(f32x4*)(sab + (long)kc * HW_ + p0) = v;
        float bz = Bz[kc];
        float a0 = __expf((v[0] + bz) * ALPHA_ - Zm[p0])     * Iv[p0];
        float a1 = __expf((v[1] + bz) * ALPHA_ - Zm[p0 + 1]) * Iv[p0 + 1];
        float a2 = __expf((v[2] + bz) * ALPHA_ - Zm[p0 + 2]) * Iv[p0 + 2];
        float a3 = __expf((v[3] + bz) * ALPHA_ - Zm[p0 + 3]) * Iv[p0 + 3];
        uint2 u;
        u.x = (unsigned)f2bf(a0) | ((unsigned)f2bf(a1) << 16);
        u.y = (unsigned)f2bf(a2) | ((unsigned)f2bf(a3) << 16);
        *(uint2*)(Arow + (long)kc * HW_ + p0) = u;
        Ls[kc * LSP + p0]     = a0;           // keep a for the sumA reduction
        Ls[kc * LSP + p0 + 1] = a1;
        Ls[kc * LSP + p0 + 2] = a2;
        Ls[kc * LSP + p0 + 3] = a3;
    }
    __syncthreads();
    if (t < 64) {
        float s = 0.f;
#pragma unroll
        for (int p = 0; p < 16; ++p) s += Ls[t * LSP + p];
        sumA_part[((long)n * 64 + tile) * 64 + t] = s;
    }
}

// ---------------- K4: MFMA GEMM2 vlad_raw = A . (x*invn) (scale+cvt in staging)
#define K4PITCH 72    // bf16; 144 B rows, 16B aligned
__global__ __launch_bounds__(256, 4) void k4_vlad(const float* __restrict__ x,
                                                  const float* __restrict__ invn,
                                                  const unsigned short* __restrict__ Ab,
                                                  float* __restrict__ part) {
    __shared__ float invs[512];
    __shared__ alignas(16) unsigned short Ash[64 * K4PITCH];    // 9216 B
    __shared__ alignas(16) unsigned short Fsh[64 * K4PITCH];    // 9216 B
    int b  = blockIdx.x;
    int n  = b >> 4;
    int r  = b & 15;
    int c_off  = (r & 7) * 64;
    int hh     = r >> 3;
    int h_base = hh * 512;
    int t = threadIdx.x;
    int l = t & 63, w = t >> 6;
    int mr = l & 15, q = l >> 4;
    int kcb = (w >> 1) * 32, cb = (w & 1) * 32;

    invs[t]       = invn[(long)n * HW_ + h_base + t];
    invs[t + 256] = invn[(long)n * HW_ + h_base + 256 + t];

    f32x4 acc[2][2];
#pragma unroll
    for (int i = 0; i < 2; ++i)
#pragma unroll
        for (int j = 0; j < 2; ++j) acc[i][j] = (f32x4){0.f, 0.f, 0.f, 0.f};

    const unsigned short* Abase = Ab + (long)n * K_ * HW_ + h_base;
    const float* xbase = x + ((long)n * C_ + c_off) * HW_ + h_base;

    for (int ch = 0; ch < 8; ++ch) {
        int h0 = ch * 64;
        __syncthreads();
#pragma unroll
        for (int j = 0; j < 2; ++j) {          // Ash: 64kc x 64h (bf16 copy)
            int idx = j * 256 + t;
            int row = idx >> 3, sg = idx & 7;
            *(uint4*)(Ash + row * K4PITCH + sg * 8) =
                *(const uint4*)(Abase + (long)row * HW_ + h0 + sg * 8);
        }
#pragma unroll
        for (int j = 0; j < 2; ++j) {          // Fsh: 64c x 64h (x*invn -> bf16)
            int idx = j * 256 + t;
            int row = idx >> 3, sg = idx & 7;
            const float* src = xbase + (long)row * HW_ + h0 + sg * 8;
            float4 v0 = *(const float4*)src;
            float4 v1 = *(const float4*)(src + 4);
            const float* iv = invs + h0 + sg * 8;
            ushort8v pk;
            pk[0] = f2bf(v0.x * iv[0]); pk[1] = f2bf(v0.y * iv[1]);
            pk[2] = f2bf(v0.z * iv[2]); pk[3] = f2bf(v0.w * iv[3]);
            pk[4] = f2bf(v1.x * iv[4]); pk[5] = f2bf(v1.y * iv[5]);
            pk[6] = f2bf(v1.z * iv[6]); pk[7] = f2bf(v1.w * iv[7]);
            *(ushort8v*)(Fsh + row * K4PITCH + sg * 8) = pk;
        }
        __syncthreads();
#pragma unroll
        for (int ks = 0; ks < 2; ++ks) {
            int ko = ks * 32 + q * 8;
            const unsigned short* ap0 = Ash + (kcb + mr) * K4PITCH + ko;
            const unsigned short* ap1 = Ash + (kcb + 16 + mr) * K4PITCH + ko;
#pragma unroll
            for (int j = 0; j < 2; ++j) {
                const unsigned short* bp = Fsh + (cb + j * 16 + mr) * K4PITCH + ko;
                acc[0][j] = mfma16(ap0, bp, acc[0][j]);
                acc[1][j] = mfma16(ap1, bp, acc[1][j]);
            }
        }
    }
    float* pb = part + (long)hh * PART_ELEMS + (long)n * K_ * C_ + c_off;
#pragma unroll
    for (int i = 0; i < 2; ++i)
#pragma unroll
        for (int j = 0; j < 2; ++j)
#pragma unroll
            for (int rr = 0; rr < 4; ++rr) {
                int kc = kcb + i * 16 + q * 4 + rr;
                int c  = cb + j * 16 + mr;
                pb[(long)kc * C_ + c] = acc[i][j][rr];
            }
}

// ---------------- K5: combine 2 partials, subtract sumA*W, intra-normalize
__global__ __launch_bounds__(256) void k5_norm(const float* __restrict__ part,
                                               const float* __restrict__ sumA_part,
                                               const float* __restrict__ wT,
                                               float* __restrict__ vlad) {
    __shared__ float red[256];
    __shared__ float sred[64];
    int row = blockIdx.x;        // n*64 + kc
    int kc  = row & 63;
    int n   = row >> 6;
    int t   = threadIdx.x;
    if (t < 64) sred[t] = sumA_part[((long)n * 64 + t) * 64 + kc];
    __syncthreads();
    if (t < 16) sred[t] = sred[t] + sred[t + 16] + sred[t + 32] + sred[t + 48];
    __syncthreads();
    if (t < 4) sred[t] = sred[t] + sred[t + 4] + sred[t + 8] + sred[t + 12];
    __syncthreads();
    float sA = sred[0] + sred[1] + sred[2] + sred[3];
    long base = (long)row * C_;
    float v0, v1;
    {
        int c = t;
        float s = part[base + c] + part[PART_ELEMS + base + c];
        v0 = s - sA * wT[kc * C_ + c];
    }
    {
        int c = t + 256;
        float s = part[base + c] + part[PART_ELEMS + base + c];
        v1 = s - sA * wT[kc * C_ + c];
    }
    red[t] = v0 * v0 + v1 * v1;
    __syncthreads();
    for (int st = 128; st > 0; st >>= 1) {
        if (t < st) red[t] += red[t + st];
        __syncthreads();
    }
    float inv = 1.f / fmaxf(sqrtf(red[0]), EPS_);
    vlad[base + t]       = v0 * inv;
    vlad[base + t + 256] = v1 * inv;
}

extern "C" void kernel_launch(void* const* d_in, const int* in_sizes, int n_in,
                              void* d_out, int out_size, void* d_ws, size_t ws_size,
                              hipStream_t stream) {
    const float* x    = (const float*)d_in[0];
    const float* W    = (const float*)d_in[1];
    const float* bias = (const float*)d_in[2];
    float* out = (float*)d_out;
    char* wsb  = (char*)d_ws;

    float* wT            = (float*)(wsb + WSB_WT);
    unsigned short* wnTb = (unsigned short*)(wsb + WSB_WNTB);
    float* invn          = (float*)(wsb + WSB_INVN);
    unsigned short* Ab   = (unsigned short*)(wsb + WSB_A);
    float* sumA_part     = (float*)(wsb + WSB_SAP);
    float* part          = (float*)(wsb + WSB_PART);

    float* vlad = out + OUT_VLAD;

    hipLaunchKernelGGL(k1_weights, dim3(64),   dim3(256), 0, stream, W, wT, wnTb);
    hipLaunchKernelGGL(k23_fused,  dim3(4096), dim3(256), 0, stream, x, wnTb, bias, out, invn, Ab, sumA_part);
    hipLaunchKernelGGL(k4_vlad,    dim3(1024), dim3(256), 0, stream, x, invn, Ab, part);
    hipLaunchKernelGGL(k5_norm,    dim3(4096), dim3(256), 0, stream, part, sumA_part, wT, vlad);
}